// Round 13
// baseline (3446.782 us; speedup 1.0000x reference)
//
#include <hip/hip_runtime.h>
#include <hip/hip_fp16.h>
#include <math.h>

#define NBROWS 262144
#define WS_TOT 7808

__device__ __forceinline__ unsigned ph(float a, float b){
    __half2 h = __floats2half2_rn(a, b);
    unsigned u; __builtin_memcpy(&u, &h, 4); return u;
}
__device__ __forceinline__ float2 uph(unsigned u){
    __half2 h; __builtin_memcpy(&h, &u, 4);
    return __half22float2(h);
}

__device__ __forceinline__ void pair_le(int p, int M, int& u, int& v) {
    u = 0; int cnt = M;
    while (p >= cnt) { p -= cnt; ++u; cnt = M - u; }
    v = u + p;
}
__device__ __forceinline__ void pair_lt(int p, int M, int& u, int& v) {
    u = 0; int cnt = M - 1;
    while (p >= cnt) { p -= cnt; ++u; cnt = M - 1 - u; }
    v = u + 1 + p;
}

// ---------------- packed d_ws layout (floats) — R6/R9-proven ----------------
// P1 [0,1152):     36 pairs (u<=v) x 32: [Sss w0..15][Svv0 w0..15]
// C1 [1152,2176):  (vv*8+u)*16 + w
// A1 [2176,2624):  28 pairs (u<v) x 16
// P2 [2624,4800):  136 pairs (u<=v) x 16: [Sss w0..7][Svv0 w0..7]
// C2 [4800,6848):  (vv*16+u)*8 + w
// A2 [6848,7808):  120 pairs (u<v) x 8
// All blocks 16B-aligned -> every weight read below is a single ds_read_b128
// at a wave-uniform (broadcast) address.

__global__ __launch_bounds__(256) void prep_kernel(
    const float* __restrict__ w1_ss, const float* __restrict__ w1_vv0,
    const float* __restrict__ w1_sv, const float* __restrict__ w1_vs,
    const float* __restrict__ w1_vv1,
    const float* __restrict__ w2_ss, const float* __restrict__ w2_vv0,
    const float* __restrict__ w2_sv, const float* __restrict__ w2_vs,
    const float* __restrict__ w2_vv1,
    float* __restrict__ ws)
{
    const float inv3 = 0.5773502691896258f;
    const float inv6 = 0.4082482904638631f;
    int i = blockIdx.x * 256 + threadIdx.x;
    if (i >= WS_TOT) return;
    float val = 0.f;
    if (i < 1152) {                       // P1
        int p = i >> 5, r = i & 31;
        int which = r >> 4, w = r & 15;
        int u, v; pair_le(p, 8, u, v);
        const float c0 = 0.08838834764831845f;
        const float* src = which ? w1_vv0 : w1_ss;
        float cc = which ? c0 * inv3 : c0;
        val = (u == v) ? cc * src[(u*8+v)*16+w]
                       : cc * (src[(u*8+v)*16+w] + src[(v*8+u)*16+w]);
    } else if (i < 2176) {                // C1
        int r = i - 1152; int vv = r >> 7, rem = r & 127, u = rem >> 4, w = rem & 15;
        val = (0.125f * inv3) * (w1_sv[(u*8+vv)*16+w] + w1_vs[(vv*8+u)*16+w]);
    } else if (i < 2624) {                // A1
        int r = i - 2176; int p = r >> 4, w = r & 15;
        int u, v; pair_lt(p, 8, u, v);
        val = (0.125f * inv6) * (w1_vv1[(u*8+v)*16+w] - w1_vv1[(v*8+u)*16+w]);
    } else if (i < 4800) {                // P2
        int r = i - 2624; int p = r >> 4, rr = r & 15, which = rr >> 3, w = rr & 7;
        int u, v; pair_le(p, 16, u, v);
        const float c0 = 0.04419417382415922f;
        const float* src = which ? w2_vv0 : w2_ss;
        float cc = which ? c0 * inv3 : c0;
        val = (u == v) ? cc * src[(u*16+v)*8+w]
                       : cc * (src[(u*16+v)*8+w] + src[(v*16+u)*8+w]);
    } else if (i < 6848) {                // C2
        int r = i - 4800; int vv = r >> 7, rem = r & 127, u = rem >> 3, w = rem & 7;
        val = (0.0625f * inv3) * (w2_sv[(u*16+vv)*8+w] + w2_vs[(vv*16+u)*8+w]);
    } else {                              // A2
        int r = i - 6848; int p = r >> 3, w = r & 7;
        int u, v; pair_lt(p, 16, u, v);
        val = (0.0625f * inv6) * (w2_vv1[(u*16+v)*8+w] - w2_vv1[(v*16+u)*8+w]);
    }
    ws[i] = val;
}

// ---------------- layer 1: 8 -> 16, chunk of 8 outputs, b128 reads ----------
template<int W0>
__device__ __forceinline__ void l1_chunk(const float* Wl,
    const float (&s)[8], const float (&v)[8][3],
    float (&ys)[16], float (&ox)[16], float (&oy)[16], float (&oz)[16])
{
#pragma unroll
    for (int w = 0; w < 8; ++w) { ys[W0+w]=0.f; ox[W0+w]=0.f; oy[W0+w]=0.f; oz[W0+w]=0.f; }
    {   // symmetric ss + vv0: 4 b128 per pair
        int p = 0;
#pragma unroll
        for (int u = 0; u < 8; ++u)
#pragma unroll
        for (int vv = u; vv < 8; ++vv) {
            float pp = s[u] * s[vv];
            float dd = v[u][0]*v[vv][0] + v[u][1]*v[vv][1] + v[u][2]*v[vv][2];
            const float4* qa = reinterpret_cast<const float4*>(Wl + p*32 + W0);
            const float4* qb = reinterpret_cast<const float4*>(Wl + p*32 + 16 + W0);
            float4 a0 = qa[0], a1 = qa[1], b0 = qb[0], b1 = qb[1];
            ys[W0+0] += pp*a0.x + dd*b0.x;  ys[W0+1] += pp*a0.y + dd*b0.y;
            ys[W0+2] += pp*a0.z + dd*b0.z;  ys[W0+3] += pp*a0.w + dd*b0.w;
            ys[W0+4] += pp*a1.x + dd*b1.x;  ys[W0+5] += pp*a1.y + dd*b1.y;
            ys[W0+6] += pp*a1.z + dd*b1.z;  ys[W0+7] += pp*a1.w + dd*b1.w;
            ++p;
        }
    }
    // combined sv+vs: 2 b128 per (vv,u)
#pragma unroll
    for (int vv = 0; vv < 8; ++vv) {
        float tw[8];
#pragma unroll
        for (int w = 0; w < 8; ++w) tw[w] = 0.f;
#pragma unroll
        for (int u = 0; u < 8; ++u) {
            const float4* qc = reinterpret_cast<const float4*>(Wl + 1152 + (vv*8+u)*16 + W0);
            float4 c0 = qc[0], c1 = qc[1];
            float su = s[u];
            tw[0] += su*c0.x; tw[1] += su*c0.y; tw[2] += su*c0.z; tw[3] += su*c0.w;
            tw[4] += su*c1.x; tw[5] += su*c1.y; tw[6] += su*c1.z; tw[7] += su*c1.w;
        }
#pragma unroll
        for (int w = 0; w < 8; ++w) {
            ox[W0+w] += tw[w] * v[vv][0];
            oy[W0+w] += tw[w] * v[vv][1];
            oz[W0+w] += tw[w] * v[vv][2];
        }
    }
    {   // antisymmetric cross: 2 b128 per pair
        int p = 0;
#pragma unroll
        for (int u = 0; u < 8; ++u)
#pragma unroll
        for (int vv = u + 1; vv < 8; ++vv) {
            float cx = v[u][1]*v[vv][2] - v[u][2]*v[vv][1];
            float cy = v[u][2]*v[vv][0] - v[u][0]*v[vv][2];
            float cz = v[u][0]*v[vv][1] - v[u][1]*v[vv][0];
            const float4* qa = reinterpret_cast<const float4*>(Wl + 2176 + p*16 + W0);
            float4 a0 = qa[0], a1 = qa[1];
            ox[W0+0] += a0.x*cx; oy[W0+0] += a0.x*cy; oz[W0+0] += a0.x*cz;
            ox[W0+1] += a0.y*cx; oy[W0+1] += a0.y*cy; oz[W0+1] += a0.y*cz;
            ox[W0+2] += a0.z*cx; oy[W0+2] += a0.z*cy; oz[W0+2] += a0.z*cz;
            ox[W0+3] += a0.w*cx; oy[W0+3] += a0.w*cy; oz[W0+3] += a0.w*cz;
            ox[W0+4] += a1.x*cx; oy[W0+4] += a1.x*cy; oz[W0+4] += a1.x*cz;
            ox[W0+5] += a1.y*cx; oy[W0+5] += a1.y*cy; oz[W0+5] += a1.y*cz;
            ox[W0+6] += a1.z*cx; oy[W0+6] += a1.z*cy; oz[W0+6] += a1.z*cz;
            ox[W0+7] += a1.w*cx; oy[W0+7] += a1.w*cy; oz[W0+7] += a1.w*cz;
            ++p;
        }
    }
}

// ---------------- layer 2: 16 -> 8, single pass, b128 reads -----------------
// LDS window rebased: P2 at 0, C2 at 2176, A2 at 4224.
__device__ __forceinline__ void l2_pass(const float* Wl,
    const float (&s)[16], const float (&vx)[16], const float (&vy)[16], const float (&vz)[16],
    float (&zs)[8], float (&zx)[8], float (&zy)[8], float (&zz)[8])
{
#pragma unroll
    for (int w = 0; w < 8; ++w) { zs[w]=0.f; zx[w]=0.f; zy[w]=0.f; zz[w]=0.f; }
    {   // symmetric: 4 b128 per pair
        int p = 0;
#pragma unroll
        for (int u = 0; u < 16; ++u)
#pragma unroll
        for (int vv = u; vv < 16; ++vv) {
            float pp = s[u] * s[vv];
            float dd = vx[u]*vx[vv] + vy[u]*vy[vv] + vz[u]*vz[vv];
            const float4* q = reinterpret_cast<const float4*>(Wl + p*16);
            float4 a0 = q[0], a1 = q[1], b0 = q[2], b1 = q[3];
            zs[0] += pp*a0.x + dd*b0.x;  zs[1] += pp*a0.y + dd*b0.y;
            zs[2] += pp*a0.z + dd*b0.z;  zs[3] += pp*a0.w + dd*b0.w;
            zs[4] += pp*a1.x + dd*b1.x;  zs[5] += pp*a1.y + dd*b1.y;
            zs[6] += pp*a1.z + dd*b1.z;  zs[7] += pp*a1.w + dd*b1.w;
            ++p;
        }
    }
#pragma unroll
    for (int vv = 0; vv < 16; ++vv) {
        float tw[8];
#pragma unroll
        for (int w = 0; w < 8; ++w) tw[w] = 0.f;
#pragma unroll
        for (int u = 0; u < 16; ++u) {
            const float4* qc = reinterpret_cast<const float4*>(Wl + 2176 + (vv*16+u)*8);
            float4 c0 = qc[0], c1 = qc[1];
            float su = s[u];
            tw[0] += su*c0.x; tw[1] += su*c0.y; tw[2] += su*c0.z; tw[3] += su*c0.w;
            tw[4] += su*c1.x; tw[5] += su*c1.y; tw[6] += su*c1.z; tw[7] += su*c1.w;
        }
#pragma unroll
        for (int w = 0; w < 8; ++w) {
            zx[w] += tw[w] * vx[vv];
            zy[w] += tw[w] * vy[vv];
            zz[w] += tw[w] * vz[vv];
        }
    }
    {   // cross: 2 b128 per pair
        int p = 0;
#pragma unroll
        for (int u = 0; u < 16; ++u)
#pragma unroll
        for (int vv = u + 1; vv < 16; ++vv) {
            float cx = vy[u]*vz[vv] - vz[u]*vy[vv];
            float cy = vz[u]*vx[vv] - vx[u]*vz[vv];
            float cz = vx[u]*vy[vv] - vy[u]*vx[vv];
            const float4* qa = reinterpret_cast<const float4*>(Wl + 4224 + p*8);
            float4 a0 = qa[0], a1 = qa[1];
            zx[0] += a0.x*cx; zy[0] += a0.x*cy; zz[0] += a0.x*cz;
            zx[1] += a0.y*cx; zy[1] += a0.y*cy; zz[1] += a0.y*cz;
            zx[2] += a0.z*cx; zy[2] += a0.z*cy; zz[2] += a0.z*cz;
            zx[3] += a0.w*cx; zy[3] += a0.w*cy; zz[3] += a0.w*cz;
            zx[4] += a1.x*cx; zy[4] += a1.x*cy; zz[4] += a1.x*cz;
            zx[5] += a1.y*cx; zy[5] += a1.y*cy; zz[5] += a1.y*cz;
            zx[6] += a1.z*cx; zy[6] += a1.z*cy; zz[6] += a1.z*cz;
            zx[7] += a1.w*cx; zy[7] += a1.w*cy; zz[7] += a1.w*cz;
            ++p;
        }
    }
}

// ---------------- scalar norms (R11-proven) ----------------
__device__ __forceinline__ void si_norm16_s(float (&ys)[16], float (&ox)[16], float (&oy)[16], float (&oz)[16])
{
    float sum = 0.f;
#pragma unroll
    for (int i = 0; i < 16; ++i) sum += ys[i];
    float m = sum * (1.f/16);
    float var = 0.f;
#pragma unroll
    for (int i = 0; i < 16; ++i) { float d = ys[i] - m; var += d*d; }
    float inv = 1.f / (sqrtf(var * (1.f/15)) + 1e-9f);
#pragma unroll
    for (int i = 0; i < 16; ++i) ys[i] *= inv;

    float n1[16]; float sn = 0.f;
#pragma unroll
    for (int i = 0; i < 16; ++i) {
        n1[i] = sqrtf(ox[i]*ox[i] + oy[i]*oy[i] + oz[i]*oz[i] + 1e-9f);
        sn += n1[i];
    }
    float mn = sn * (1.f/16);
    float vr = 0.f;
#pragma unroll
    for (int i = 0; i < 16; ++i) { float d = n1[i] - mn; vr += d*d; }
    float invv = 1.f / (sqrtf(vr * (1.f/15)) + 1e-9f);
#pragma unroll
    for (int i = 0; i < 16; ++i) { ox[i] *= invv; oy[i] *= invv; oz[i] *= invv; }
}

__device__ __forceinline__ void tv_norm16_s(float (&ys)[16], float (&ox)[16], float (&oy)[16], float (&oz)[16])
{
    float ss = 0.f;
#pragma unroll
    for (int i = 0; i < 16; ++i) ss += ys[i]*ys[i];
    float inv = 1.f / sqrtf(ss + 1e-6f);
#pragma unroll
    for (int i = 0; i < 16; ++i) ys[i] *= inv;

    float a0 = 0.f, a1 = 0.f, a2 = 0.f;
#pragma unroll
    for (int i = 0; i < 16; ++i) { a0 += ox[i]*ox[i]; a1 += oy[i]*oy[i]; a2 += oz[i]*oz[i]; }
    float nm = (sqrtf(a0+1e-6f) + sqrtf(a1+1e-6f) + sqrtf(a2+1e-6f)) * (1.f/3.f);
    float invv = 1.f / (nm + 1e-6f);
#pragma unroll
    for (int i = 0; i < 16; ++i) { ox[i] *= invv; oy[i] *= invv; oz[i] *= invv; }
}

__device__ __forceinline__ void si_norm8_s(float (&zs)[8], float (&zx)[8], float (&zy)[8], float (&zz)[8])
{
    float sum = 0.f;
#pragma unroll
    for (int i = 0; i < 8; ++i) sum += zs[i];
    float m = sum * (1.f/8);
    float var = 0.f;
#pragma unroll
    for (int i = 0; i < 8; ++i) { float d = zs[i] - m; var += d*d; }
    float inv = 1.f / (sqrtf(var * (1.f/7)) + 1e-9f);
#pragma unroll
    for (int i = 0; i < 8; ++i) zs[i] *= inv;

    float n1[8]; float sn = 0.f;
#pragma unroll
    for (int i = 0; i < 8; ++i) {
        n1[i] = sqrtf(zx[i]*zx[i] + zy[i]*zy[i] + zz[i]*zz[i] + 1e-9f);
        sn += n1[i];
    }
    float mn = sn * (1.f/8);
    float vr = 0.f;
#pragma unroll
    for (int i = 0; i < 8; ++i) { float d = n1[i] - mn; vr += d*d; }
    float invv = 1.f / (sqrtf(vr * (1.f/7)) + 1e-9f);
#pragma unroll
    for (int i = 0; i < 8; ++i) { zx[i] *= invv; zy[i] *= invv; zz[i] *= invv; }
}

__device__ __forceinline__ float fast_tanh(float x) {
    return 1.f - 2.f / (__expf(2.f * x) + 1.f);
}

// ================= Kernel A: layer 1 + si_norm + tv_norm =====================
__global__ __launch_bounds__(256) void DoubleLayer_l1_kernel(
    const float* __restrict__ x,
    const float* __restrict__ ws,
    unsigned* __restrict__ inter)
{
    __shared__ float Wl[2624];

    int t = threadIdx.x;
    int row = blockIdx.x * 256 + t;
    const float4* xr = reinterpret_cast<const float4*>(x + (size_t)row * 32);
    float4 q0 = xr[0], q1 = xr[1], q2 = xr[2], q3 = xr[3];
    float4 q4 = xr[4], q5 = xr[5], q6 = xr[6], q7 = xr[7];

#pragma unroll
    for (int i = 0; i < 3; ++i) {
        int idx = t + i * 256;
        if (idx < 656)
            reinterpret_cast<float4*>(Wl)[idx] = reinterpret_cast<const float4*>(ws)[idx];
    }
    __syncthreads();

    float s1[8];
    s1[0] = fast_tanh(q0.x); s1[1] = fast_tanh(q0.y); s1[2] = fast_tanh(q0.z); s1[3] = fast_tanh(q0.w);
    s1[4] = fast_tanh(q1.x); s1[5] = fast_tanh(q1.y); s1[6] = fast_tanh(q1.z); s1[7] = fast_tanh(q1.w);
    float v1[8][3];
    v1[0][0]=q2.x; v1[0][1]=q2.y; v1[0][2]=q2.z;
    v1[1][0]=q2.w; v1[1][1]=q3.x; v1[1][2]=q3.y;
    v1[2][0]=q3.z; v1[2][1]=q3.w; v1[2][2]=q4.x;
    v1[3][0]=q4.y; v1[3][1]=q4.z; v1[3][2]=q4.w;
    v1[4][0]=q5.x; v1[4][1]=q5.y; v1[4][2]=q5.z;
    v1[5][0]=q5.w; v1[5][1]=q6.x; v1[5][2]=q6.y;
    v1[6][0]=q6.z; v1[6][1]=q6.w; v1[6][2]=q7.x;
    v1[7][0]=q7.y; v1[7][1]=q7.z; v1[7][2]=q7.w;

    float ys[16], ox[16], oy[16], oz[16];
    l1_chunk<0>(Wl, s1, v1, ys, ox, oy, oz);
    __builtin_amdgcn_sched_barrier(0);
    l1_chunk<8>(Wl, s1, v1, ys, ox, oy, oz);
    __builtin_amdgcn_sched_barrier(0);

    si_norm16_s(ys, ox, oy, oz);
    tv_norm16_s(ys, ox, oy, oz);

    uint4* o4 = reinterpret_cast<uint4*>(inter + (size_t)row * 32);
    o4[0] = make_uint4(ph(ys[0],ys[1]),  ph(ys[2],ys[3]),  ph(ys[4],ys[5]),  ph(ys[6],ys[7]));
    o4[1] = make_uint4(ph(ys[8],ys[9]),  ph(ys[10],ys[11]),ph(ys[12],ys[13]),ph(ys[14],ys[15]));
    o4[2] = make_uint4(ph(ox[0],ox[1]),  ph(ox[2],ox[3]),  ph(ox[4],ox[5]),  ph(ox[6],ox[7]));
    o4[3] = make_uint4(ph(ox[8],ox[9]),  ph(ox[10],ox[11]),ph(ox[12],ox[13]),ph(ox[14],ox[15]));
    o4[4] = make_uint4(ph(oy[0],oy[1]),  ph(oy[2],oy[3]),  ph(oy[4],oy[5]),  ph(oy[6],oy[7]));
    o4[5] = make_uint4(ph(oy[8],oy[9]),  ph(oy[10],oy[11]),ph(oy[12],oy[13]),ph(oy[14],oy[15]));
    o4[6] = make_uint4(ph(oz[0],oz[1]),  ph(oz[2],oz[3]),  ph(oz[4],oz[5]),  ph(oz[6],oz[7]));
    o4[7] = make_uint4(ph(oz[8],oz[9]),  ph(oz[10],oz[11]),ph(oz[12],oz[13]),ph(oz[14],oz[15]));
}

// ================= Kernel B: layer 2 + si_norm + sigmoid =====================
__global__ __launch_bounds__(256) void DoubleLayer_l2_kernel(
    const float* __restrict__ ws,
    float* __restrict__ out)
{
    __shared__ float Wl[5184];

    int t = threadIdx.x;
    int row = blockIdx.x * 256 + t;
    const uint4* irow = reinterpret_cast<const uint4*>(out + (size_t)row * 32);
    uint4 h0 = irow[0], h1 = irow[1], h2 = irow[2], h3 = irow[3];
    uint4 h4 = irow[4], h5 = irow[5], h6 = irow[6], h7 = irow[7];

    const float4* wsrc = reinterpret_cast<const float4*>(ws + 2624);
#pragma unroll
    for (int i = 0; i < 6; ++i) {
        int idx = t + i * 256;
        if (idx < 1296)
            reinterpret_cast<float4*>(Wl)[idx] = wsrc[idx];
    }
    __syncthreads();

    float s2[16], vx[16], vy[16], vz[16];
    {
        unsigned us[8] = {h0.x,h0.y,h0.z,h0.w,h1.x,h1.y,h1.z,h1.w};
        unsigned ux[8] = {h2.x,h2.y,h2.z,h2.w,h3.x,h3.y,h3.z,h3.w};
        unsigned uy[8] = {h4.x,h4.y,h4.z,h4.w,h5.x,h5.y,h5.z,h5.w};
        unsigned uz[8] = {h6.x,h6.y,h6.z,h6.w,h7.x,h7.y,h7.z,h7.w};
#pragma unroll
        for (int j = 0; j < 8; ++j) {
            float2 fs = uph(us[j]); s2[2*j] = fs.x; s2[2*j+1] = fs.y;
            float2 fx = uph(ux[j]); vx[2*j] = fx.x; vx[2*j+1] = fx.y;
            float2 fy = uph(uy[j]); vy[2*j] = fy.x; vy[2*j+1] = fy.y;
            float2 fz = uph(uz[j]); vz[2*j] = fz.x; vz[2*j+1] = fz.y;
        }
    }
    __builtin_amdgcn_sched_barrier(0);

    float zs[8], zx[8], zy[8], zz[8];
    l2_pass(Wl, s2, vx, vy, vz, zs, zx, zy, zz);
    __builtin_amdgcn_sched_barrier(0);

    si_norm8_s(zs, zx, zy, zz);

    float o[32];
#pragma unroll
    for (int w = 0; w < 8; ++w) o[w] = 1.f / (1.f + __expf(-zs[w]));
#pragma unroll
    for (int w = 0; w < 8; ++w) {
        o[8+3*w+0] = zx[w]; o[8+3*w+1] = zy[w]; o[8+3*w+2] = zz[w];
    }
    float4* orow = reinterpret_cast<float4*>(out + (size_t)row * 32);
#pragma unroll
    for (int i = 0; i < 8; ++i) orow[i] = make_float4(o[4*i+0], o[4*i+1], o[4*i+2], o[4*i+3]);
}

extern "C" void kernel_launch(void* const* d_in, const int* in_sizes, int n_in,
                              void* d_out, int out_size, void* d_ws, size_t ws_size,
                              hipStream_t stream)
{
    const float* x = (const float*)d_in[0];
    float* ws = (float*)d_ws;
    prep_kernel<<<31, 256, 0, stream>>>(
        (const float*)d_in[1], (const float*)d_in[2], (const float*)d_in[3],
        (const float*)d_in[4], (const float*)d_in[5],
        (const float*)d_in[6], (const float*)d_in[7], (const float*)d_in[8],
        (const float*)d_in[9], (const float*)d_in[10], ws);
    DoubleLayer_l1_kernel<<<NBROWS/256, 256, 0, stream>>>(x, ws, (unsigned*)d_out);
    DoubleLayer_l2_kernel<<<NBROWS/256, 256, 0, stream>>>(ws, (float*)d_out);
}

// Round 14
// 2325.153 us; speedup vs baseline: 1.4824x; 1.4824x over previous
//
#include <hip/hip_runtime.h>
#include <hip/hip_fp16.h>
#include <math.h>

#define NBROWS 262144
#define WS_TOT 7808

#define FENCE() __builtin_amdgcn_sched_barrier(0)

__device__ __forceinline__ unsigned ph(float a, float b){
    __half2 h = __floats2half2_rn(a, b);
    unsigned u; __builtin_memcpy(&u, &h, 4); return u;
}
__device__ __forceinline__ float2 uph(unsigned u){
    __half2 h; __builtin_memcpy(&h, &u, 4);
    return __half22float2(h);
}

__device__ __forceinline__ void pair_le(int p, int M, int& u, int& v) {
    u = 0; int cnt = M;
    while (p >= cnt) { p -= cnt; ++u; cnt = M - u; }
    v = u + p;
}
__device__ __forceinline__ void pair_lt(int p, int M, int& u, int& v) {
    u = 0; int cnt = M - 1;
    while (p >= cnt) { p -= cnt; ++u; cnt = M - 1 - u; }
    v = u + 1 + p;
}

// ---------------- packed d_ws layout (floats) — R6/R9-proven ----------------
// P1 [0,1152):     36 pairs (u<=v) x 32: [Sss w0..15][Svv0 w0..15]
// C1 [1152,2176):  (vv*8+u)*16 + w
// A1 [2176,2624):  28 pairs (u<v) x 16
// P2 [2624,4800):  136 pairs (u<=v) x 16: [Sss w0..7][Svv0 w0..7]
// C2 [4800,6848):  (vv*16+u)*8 + w
// A2 [6848,7808):  120 pairs (u<v) x 8

__global__ __launch_bounds__(256) void prep_kernel(
    const float* __restrict__ w1_ss, const float* __restrict__ w1_vv0,
    const float* __restrict__ w1_sv, const float* __restrict__ w1_vs,
    const float* __restrict__ w1_vv1,
    const float* __restrict__ w2_ss, const float* __restrict__ w2_vv0,
    const float* __restrict__ w2_sv, const float* __restrict__ w2_vs,
    const float* __restrict__ w2_vv1,
    float* __restrict__ ws)
{
    const float inv3 = 0.5773502691896258f;
    const float inv6 = 0.4082482904638631f;
    int i = blockIdx.x * 256 + threadIdx.x;
    if (i >= WS_TOT) return;
    float val = 0.f;
    if (i < 1152) {                       // P1
        int p = i >> 5, r = i & 31;
        int which = r >> 4, w = r & 15;
        int u, v; pair_le(p, 8, u, v);
        const float c0 = 0.08838834764831845f;
        const float* src = which ? w1_vv0 : w1_ss;
        float cc = which ? c0 * inv3 : c0;
        val = (u == v) ? cc * src[(u*8+v)*16+w]
                       : cc * (src[(u*8+v)*16+w] + src[(v*8+u)*16+w]);
    } else if (i < 2176) {                // C1
        int r = i - 1152; int vv = r >> 7, rem = r & 127, u = rem >> 4, w = rem & 15;
        val = (0.125f * inv3) * (w1_sv[(u*8+vv)*16+w] + w1_vs[(vv*8+u)*16+w]);
    } else if (i < 2624) {                // A1
        int r = i - 2176; int p = r >> 4, w = r & 15;
        int u, v; pair_lt(p, 8, u, v);
        val = (0.125f * inv6) * (w1_vv1[(u*8+v)*16+w] - w1_vv1[(v*8+u)*16+w]);
    } else if (i < 4800) {                // P2
        int r = i - 2624; int p = r >> 4, rr = r & 15, which = rr >> 3, w = rr & 7;
        int u, v; pair_le(p, 16, u, v);
        const float c0 = 0.04419417382415922f;
        const float* src = which ? w2_vv0 : w2_ss;
        float cc = which ? c0 * inv3 : c0;
        val = (u == v) ? cc * src[(u*16+v)*8+w]
                       : cc * (src[(u*16+v)*8+w] + src[(v*16+u)*8+w]);
    } else if (i < 6848) {                // C2
        int r = i - 4800; int vv = r >> 7, rem = r & 127, u = rem >> 3, w = rem & 7;
        val = (0.0625f * inv3) * (w2_sv[(u*16+vv)*8+w] + w2_vs[(vv*16+u)*8+w]);
    } else {                              // A2
        int r = i - 6848; int p = r >> 3, w = r & 7;
        int u, v; pair_lt(p, 16, u, v);
        val = (0.0625f * inv6) * (w2_vv1[(u*16+v)*8+w] - w2_vv1[(v*16+u)*8+w]);
    }
    ws[i] = val;
}

// ---------------- layer 1: 8 -> 16, chunk of 8 outputs, b128 + per-iter fence
template<int W0>
__device__ __forceinline__ void l1_chunk(const float* Wl,
    const float (&s)[8], const float (&v)[8][3],
    float (&ys)[16], float (&ox)[16], float (&oy)[16], float (&oz)[16])
{
#pragma unroll
    for (int w = 0; w < 8; ++w) { ys[W0+w]=0.f; ox[W0+w]=0.f; oy[W0+w]=0.f; oz[W0+w]=0.f; }
    {   // symmetric ss + vv0: 4 b128 per pair, fence per pair
        int p = 0;
#pragma unroll
        for (int u = 0; u < 8; ++u)
#pragma unroll
        for (int vv = u; vv < 8; ++vv) {
            float pp = s[u] * s[vv];
            float dd = v[u][0]*v[vv][0] + v[u][1]*v[vv][1] + v[u][2]*v[vv][2];
            const float4* qa = reinterpret_cast<const float4*>(Wl + p*32 + W0);
            const float4* qb = reinterpret_cast<const float4*>(Wl + p*32 + 16 + W0);
            float4 a0 = qa[0], a1 = qa[1], b0 = qb[0], b1 = qb[1];
            ys[W0+0] += pp*a0.x + dd*b0.x;  ys[W0+1] += pp*a0.y + dd*b0.y;
            ys[W0+2] += pp*a0.z + dd*b0.z;  ys[W0+3] += pp*a0.w + dd*b0.w;
            ys[W0+4] += pp*a1.x + dd*b1.x;  ys[W0+5] += pp*a1.y + dd*b1.y;
            ys[W0+6] += pp*a1.z + dd*b1.z;  ys[W0+7] += pp*a1.w + dd*b1.w;
            ++p;
            FENCE();
        }
    }
    // combined sv+vs: 2 b128 per (vv,u), fence per u
#pragma unroll
    for (int vv = 0; vv < 8; ++vv) {
        float tw[8];
#pragma unroll
        for (int w = 0; w < 8; ++w) tw[w] = 0.f;
#pragma unroll
        for (int u = 0; u < 8; ++u) {
            const float4* qc = reinterpret_cast<const float4*>(Wl + 1152 + (vv*8+u)*16 + W0);
            float4 c0 = qc[0], c1 = qc[1];
            float su = s[u];
            tw[0] += su*c0.x; tw[1] += su*c0.y; tw[2] += su*c0.z; tw[3] += su*c0.w;
            tw[4] += su*c1.x; tw[5] += su*c1.y; tw[6] += su*c1.z; tw[7] += su*c1.w;
            FENCE();
        }
#pragma unroll
        for (int w = 0; w < 8; ++w) {
            ox[W0+w] += tw[w] * v[vv][0];
            oy[W0+w] += tw[w] * v[vv][1];
            oz[W0+w] += tw[w] * v[vv][2];
        }
        FENCE();
    }
    {   // antisymmetric cross: 2 b128 per pair, fence per pair
        int p = 0;
#pragma unroll
        for (int u = 0; u < 8; ++u)
#pragma unroll
        for (int vv = u + 1; vv < 8; ++vv) {
            float cx = v[u][1]*v[vv][2] - v[u][2]*v[vv][1];
            float cy = v[u][2]*v[vv][0] - v[u][0]*v[vv][2];
            float cz = v[u][0]*v[vv][1] - v[u][1]*v[vv][0];
            const float4* qa = reinterpret_cast<const float4*>(Wl + 2176 + p*16 + W0);
            float4 a0 = qa[0], a1 = qa[1];
            ox[W0+0] += a0.x*cx; oy[W0+0] += a0.x*cy; oz[W0+0] += a0.x*cz;
            ox[W0+1] += a0.y*cx; oy[W0+1] += a0.y*cy; oz[W0+1] += a0.y*cz;
            ox[W0+2] += a0.z*cx; oy[W0+2] += a0.z*cy; oz[W0+2] += a0.z*cz;
            ox[W0+3] += a0.w*cx; oy[W0+3] += a0.w*cy; oz[W0+3] += a0.w*cz;
            ox[W0+4] += a1.x*cx; oy[W0+4] += a1.x*cy; oz[W0+4] += a1.x*cz;
            ox[W0+5] += a1.y*cx; oy[W0+5] += a1.y*cy; oz[W0+5] += a1.y*cz;
            ox[W0+6] += a1.z*cx; oy[W0+6] += a1.z*cy; oz[W0+6] += a1.z*cz;
            ox[W0+7] += a1.w*cx; oy[W0+7] += a1.w*cy; oz[W0+7] += a1.w*cz;
            ++p;
            FENCE();
        }
    }
}

// ---------------- layer 2: 16 -> 8, single pass, b128 + per-iter fence ------
// LDS window rebased: P2 at 0, C2 at 2176, A2 at 4224.
__device__ __forceinline__ void l2_pass(const float* Wl,
    const float (&s)[16], const float (&vx)[16], const float (&vy)[16], const float (&vz)[16],
    float (&zs)[8], float (&zx)[8], float (&zy)[8], float (&zz)[8])
{
#pragma unroll
    for (int w = 0; w < 8; ++w) { zs[w]=0.f; zx[w]=0.f; zy[w]=0.f; zz[w]=0.f; }
    {   // symmetric: 4 b128 per pair, fence per pair
        int p = 0;
#pragma unroll
        for (int u = 0; u < 16; ++u)
#pragma unroll
        for (int vv = u; vv < 16; ++vv) {
            float pp = s[u] * s[vv];
            float dd = vx[u]*vx[vv] + vy[u]*vy[vv] + vz[u]*vz[vv];
            const float4* q = reinterpret_cast<const float4*>(Wl + p*16);
            float4 a0 = q[0], a1 = q[1], b0 = q[2], b1 = q[3];
            zs[0] += pp*a0.x + dd*b0.x;  zs[1] += pp*a0.y + dd*b0.y;
            zs[2] += pp*a0.z + dd*b0.z;  zs[3] += pp*a0.w + dd*b0.w;
            zs[4] += pp*a1.x + dd*b1.x;  zs[5] += pp*a1.y + dd*b1.y;
            zs[6] += pp*a1.z + dd*b1.z;  zs[7] += pp*a1.w + dd*b1.w;
            ++p;
            FENCE();
        }
    }
#pragma unroll
    for (int vv = 0; vv < 16; ++vv) {
        float tw[8];
#pragma unroll
        for (int w = 0; w < 8; ++w) tw[w] = 0.f;
#pragma unroll
        for (int u = 0; u < 16; ++u) {
            const float4* qc = reinterpret_cast<const float4*>(Wl + 2176 + (vv*16+u)*8);
            float4 c0 = qc[0], c1 = qc[1];
            float su = s[u];
            tw[0] += su*c0.x; tw[1] += su*c0.y; tw[2] += su*c0.z; tw[3] += su*c0.w;
            tw[4] += su*c1.x; tw[5] += su*c1.y; tw[6] += su*c1.z; tw[7] += su*c1.w;
            FENCE();
        }
#pragma unroll
        for (int w = 0; w < 8; ++w) {
            zx[w] += tw[w] * vx[vv];
            zy[w] += tw[w] * vy[vv];
            zz[w] += tw[w] * vz[vv];
        }
        FENCE();
    }
    {   // cross: 2 b128 per pair, fence per pair
        int p = 0;
#pragma unroll
        for (int u = 0; u < 16; ++u)
#pragma unroll
        for (int vv = u + 1; vv < 16; ++vv) {
            float cx = vy[u]*vz[vv] - vz[u]*vy[vv];
            float cy = vz[u]*vx[vv] - vx[u]*vz[vv];
            float cz = vx[u]*vy[vv] - vy[u]*vx[vv];
            const float4* qa = reinterpret_cast<const float4*>(Wl + 4224 + p*8);
            float4 a0 = qa[0], a1 = qa[1];
            zx[0] += a0.x*cx; zy[0] += a0.x*cy; zz[0] += a0.x*cz;
            zx[1] += a0.y*cx; zy[1] += a0.y*cy; zz[1] += a0.y*cz;
            zx[2] += a0.z*cx; zy[2] += a0.z*cy; zz[2] += a0.z*cz;
            zx[3] += a0.w*cx; zy[3] += a0.w*cy; zz[3] += a0.w*cz;
            zx[4] += a1.x*cx; zy[4] += a1.x*cy; zz[4] += a1.x*cz;
            zx[5] += a1.y*cx; zy[5] += a1.y*cy; zz[5] += a1.y*cz;
            zx[6] += a1.z*cx; zy[6] += a1.z*cy; zz[6] += a1.z*cz;
            zx[7] += a1.w*cx; zy[7] += a1.w*cy; zz[7] += a1.w*cz;
            ++p;
            FENCE();
        }
    }
}

// ---------------- scalar norms (R11-proven) ----------------
__device__ __forceinline__ void si_norm16_s(float (&ys)[16], float (&ox)[16], float (&oy)[16], float (&oz)[16])
{
    float sum = 0.f;
#pragma unroll
    for (int i = 0; i < 16; ++i) sum += ys[i];
    float m = sum * (1.f/16);
    float var = 0.f;
#pragma unroll
    for (int i = 0; i < 16; ++i) { float d = ys[i] - m; var += d*d; }
    float inv = 1.f / (sqrtf(var * (1.f/15)) + 1e-9f);
#pragma unroll
    for (int i = 0; i < 16; ++i) ys[i] *= inv;

    float n1[16]; float sn = 0.f;
#pragma unroll
    for (int i = 0; i < 16; ++i) {
        n1[i] = sqrtf(ox[i]*ox[i] + oy[i]*oy[i] + oz[i]*oz[i] + 1e-9f);
        sn += n1[i];
    }
    float mn = sn * (1.f/16);
    float vr = 0.f;
#pragma unroll
    for (int i = 0; i < 16; ++i) { float d = n1[i] - mn; vr += d*d; }
    float invv = 1.f / (sqrtf(vr * (1.f/15)) + 1e-9f);
#pragma unroll
    for (int i = 0; i < 16; ++i) { ox[i] *= invv; oy[i] *= invv; oz[i] *= invv; }
}

__device__ __forceinline__ void tv_norm16_s(float (&ys)[16], float (&ox)[16], float (&oy)[16], float (&oz)[16])
{
    float ss = 0.f;
#pragma unroll
    for (int i = 0; i < 16; ++i) ss += ys[i]*ys[i];
    float inv = 1.f / sqrtf(ss + 1e-6f);
#pragma unroll
    for (int i = 0; i < 16; ++i) ys[i] *= inv;

    float a0 = 0.f, a1 = 0.f, a2 = 0.f;
#pragma unroll
    for (int i = 0; i < 16; ++i) { a0 += ox[i]*ox[i]; a1 += oy[i]*oy[i]; a2 += oz[i]*oz[i]; }
    float nm = (sqrtf(a0+1e-6f) + sqrtf(a1+1e-6f) + sqrtf(a2+1e-6f)) * (1.f/3.f);
    float invv = 1.f / (nm + 1e-6f);
#pragma unroll
    for (int i = 0; i < 16; ++i) { ox[i] *= invv; oy[i] *= invv; oz[i] *= invv; }
}

__device__ __forceinline__ void si_norm8_s(float (&zs)[8], float (&zx)[8], float (&zy)[8], float (&zz)[8])
{
    float sum = 0.f;
#pragma unroll
    for (int i = 0; i < 8; ++i) sum += zs[i];
    float m = sum * (1.f/8);
    float var = 0.f;
#pragma unroll
    for (int i = 0; i < 8; ++i) { float d = zs[i] - m; var += d*d; }
    float inv = 1.f / (sqrtf(var * (1.f/7)) + 1e-9f);
#pragma unroll
    for (int i = 0; i < 8; ++i) zs[i] *= inv;

    float n1[8]; float sn = 0.f;
#pragma unroll
    for (int i = 0; i < 8; ++i) {
        n1[i] = sqrtf(zx[i]*zx[i] + zy[i]*zy[i] + zz[i]*zz[i] + 1e-9f);
        sn += n1[i];
    }
    float mn = sn * (1.f/8);
    float vr = 0.f;
#pragma unroll
    for (int i = 0; i < 8; ++i) { float d = n1[i] - mn; vr += d*d; }
    float invv = 1.f / (sqrtf(vr * (1.f/7)) + 1e-9f);
#pragma unroll
    for (int i = 0; i < 8; ++i) { zx[i] *= invv; zy[i] *= invv; zz[i] *= invv; }
}

__device__ __forceinline__ float fast_tanh(float x) {
    return 1.f - 2.f / (__expf(2.f * x) + 1.f);
}

// ================= Kernel A: layer 1 + si_norm + tv_norm =====================
__global__ __launch_bounds__(256) void DoubleLayer_l1_kernel(
    const float* __restrict__ x,
    const float* __restrict__ ws,
    unsigned* __restrict__ inter)
{
    __shared__ float Wl[2624];

    int t = threadIdx.x;
    int row = blockIdx.x * 256 + t;
    const float4* xr = reinterpret_cast<const float4*>(x + (size_t)row * 32);
    float4 q0 = xr[0], q1 = xr[1], q2 = xr[2], q3 = xr[3];
    float4 q4 = xr[4], q5 = xr[5], q6 = xr[6], q7 = xr[7];

#pragma unroll
    for (int i = 0; i < 3; ++i) {
        int idx = t + i * 256;
        if (idx < 656)
            reinterpret_cast<float4*>(Wl)[idx] = reinterpret_cast<const float4*>(ws)[idx];
    }
    __syncthreads();

    float s1[8];
    s1[0] = fast_tanh(q0.x); s1[1] = fast_tanh(q0.y); s1[2] = fast_tanh(q0.z); s1[3] = fast_tanh(q0.w);
    s1[4] = fast_tanh(q1.x); s1[5] = fast_tanh(q1.y); s1[6] = fast_tanh(q1.z); s1[7] = fast_tanh(q1.w);
    float v1[8][3];
    v1[0][0]=q2.x; v1[0][1]=q2.y; v1[0][2]=q2.z;
    v1[1][0]=q2.w; v1[1][1]=q3.x; v1[1][2]=q3.y;
    v1[2][0]=q3.z; v1[2][1]=q3.w; v1[2][2]=q4.x;
    v1[3][0]=q4.y; v1[3][1]=q4.z; v1[3][2]=q4.w;
    v1[4][0]=q5.x; v1[4][1]=q5.y; v1[4][2]=q5.z;
    v1[5][0]=q5.w; v1[5][1]=q6.x; v1[5][2]=q6.y;
    v1[6][0]=q6.z; v1[6][1]=q6.w; v1[6][2]=q7.x;
    v1[7][0]=q7.y; v1[7][1]=q7.z; v1[7][2]=q7.w;

    float ys[16], ox[16], oy[16], oz[16];
    l1_chunk<0>(Wl, s1, v1, ys, ox, oy, oz);
    FENCE();
    l1_chunk<8>(Wl, s1, v1, ys, ox, oy, oz);
    FENCE();

    si_norm16_s(ys, ox, oy, oz);
    tv_norm16_s(ys, ox, oy, oz);

    uint4* o4 = reinterpret_cast<uint4*>(inter + (size_t)row * 32);
    o4[0] = make_uint4(ph(ys[0],ys[1]),  ph(ys[2],ys[3]),  ph(ys[4],ys[5]),  ph(ys[6],ys[7]));
    o4[1] = make_uint4(ph(ys[8],ys[9]),  ph(ys[10],ys[11]),ph(ys[12],ys[13]),ph(ys[14],ys[15]));
    o4[2] = make_uint4(ph(ox[0],ox[1]),  ph(ox[2],ox[3]),  ph(ox[4],ox[5]),  ph(ox[6],ox[7]));
    o4[3] = make_uint4(ph(ox[8],ox[9]),  ph(ox[10],ox[11]),ph(ox[12],ox[13]),ph(ox[14],ox[15]));
    o4[4] = make_uint4(ph(oy[0],oy[1]),  ph(oy[2],oy[3]),  ph(oy[4],oy[5]),  ph(oy[6],oy[7]));
    o4[5] = make_uint4(ph(oy[8],oy[9]),  ph(oy[10],oy[11]),ph(oy[12],oy[13]),ph(oy[14],oy[15]));
    o4[6] = make_uint4(ph(oz[0],oz[1]),  ph(oz[2],oz[3]),  ph(oz[4],oz[5]),  ph(oz[6],oz[7]));
    o4[7] = make_uint4(ph(oz[8],oz[9]),  ph(oz[10],oz[11]),ph(oz[12],oz[13]),ph(oz[14],oz[15]));
}

// ================= Kernel B: layer 2 + si_norm + sigmoid =====================
__global__ __launch_bounds__(256) void DoubleLayer_l2_kernel(
    const float* __restrict__ ws,
    float* __restrict__ out)
{
    __shared__ float Wl[5184];

    int t = threadIdx.x;
    int row = blockIdx.x * 256 + t;
    const uint4* irow = reinterpret_cast<const uint4*>(out + (size_t)row * 32);
    uint4 h0 = irow[0], h1 = irow[1], h2 = irow[2], h3 = irow[3];
    uint4 h4 = irow[4], h5 = irow[5], h6 = irow[6], h7 = irow[7];

    const float4* wsrc = reinterpret_cast<const float4*>(ws + 2624);
#pragma unroll
    for (int i = 0; i < 6; ++i) {
        int idx = t + i * 256;
        if (idx < 1296)
            reinterpret_cast<float4*>(Wl)[idx] = wsrc[idx];
    }
    __syncthreads();

    float s2[16], vx[16], vy[16], vz[16];
    {
        unsigned us[8] = {h0.x,h0.y,h0.z,h0.w,h1.x,h1.y,h1.z,h1.w};
        unsigned ux[8] = {h2.x,h2.y,h2.z,h2.w,h3.x,h3.y,h3.z,h3.w};
        unsigned uy[8] = {h4.x,h4.y,h4.z,h4.w,h5.x,h5.y,h5.z,h5.w};
        unsigned uz[8] = {h6.x,h6.y,h6.z,h6.w,h7.x,h7.y,h7.z,h7.w};
#pragma unroll
        for (int j = 0; j < 8; ++j) {
            float2 fs = uph(us[j]); s2[2*j] = fs.x; s2[2*j+1] = fs.y;
            float2 fx = uph(ux[j]); vx[2*j] = fx.x; vx[2*j+1] = fx.y;
            float2 fy = uph(uy[j]); vy[2*j] = fy.x; vy[2*j+1] = fy.y;
            float2 fz = uph(uz[j]); vz[2*j] = fz.x; vz[2*j+1] = fz.y;
        }
    }
    FENCE();

    float zs[8], zx[8], zy[8], zz[8];
    l2_pass(Wl, s2, vx, vy, vz, zs, zx, zy, zz);
    FENCE();

    si_norm8_s(zs, zx, zy, zz);

    float o[32];
#pragma unroll
    for (int w = 0; w < 8; ++w) o[w] = 1.f / (1.f + __expf(-zs[w]));
#pragma unroll
    for (int w = 0; w < 8; ++w) {
        o[8+3*w+0] = zx[w]; o[8+3*w+1] = zy[w]; o[8+3*w+2] = zz[w];
    }
    float4* orow = reinterpret_cast<float4*>(out + (size_t)row * 32);
#pragma unroll
    for (int i = 0; i < 8; ++i) orow[i] = make_float4(o[4*i+0], o[4*i+1], o[4*i+2], o[4*i+3]);
}

extern "C" void kernel_launch(void* const* d_in, const int* in_sizes, int n_in,
                              void* d_out, int out_size, void* d_ws, size_t ws_size,
                              hipStream_t stream)
{
    const float* x = (const float*)d_in[0];
    float* ws = (float*)d_ws;
    prep_kernel<<<31, 256, 0, stream>>>(
        (const float*)d_in[1], (const float*)d_in[2], (const float*)d_in[3],
        (const float*)d_in[4], (const float*)d_in[5],
        (const float*)d_in[6], (const float*)d_in[7], (const float*)d_in[8],
        (const float*)d_in[9], (const float*)d_in[10], ws);
    DoubleLayer_l1_kernel<<<NBROWS/256, 256, 0, stream>>>(x, ws, (unsigned*)d_out);
    DoubleLayer_l2_kernel<<<NBROWS/256, 256, 0, stream>>>(ws, (float*)d_out);
}